// Round 25
// baseline (80.345 us; speedup 1.0000x reference)
//
#include <hip/hip_runtime.h>

#define NB 32
#define CC 64
#define TT 300
#define VV 25
#define HH 16
#define TPOUT 150
#define KH 4       // kernel//2
#define TC 4       // timesteps per k1 tile
#define TPB 3      // tiles per k1 block (store-drain pipelined via LDS epilogue)
#define TPG 5      // tp per fused-k2 block

#define ALD 72     // sA row stride in u16 (144 B, 16B-aligned; b128 reads 2-way free)
#define FLD 100    // sF row stride in f32

typedef __attribute__((ext_vector_type(4))) float f32x4;
typedef __attribute__((ext_vector_type(8))) short bf16x8;

static __device__ __forceinline__ unsigned short f2bf(float f) {
    unsigned u = __float_as_uint(f);
    unsigned r = (u + 0x7FFFu + ((u >> 16) & 1u)) >> 16;   // RNE
    return (unsigned short)r;
}
static __device__ __forceinline__ float bf2f(unsigned short h) {
    return __uint_as_float(((unsigned)h) << 16);
}
static __device__ __forceinline__ float bfLO(unsigned u) {
    return __uint_as_float(u << 16);
}
static __device__ __forceinline__ float bfHI(unsigned u) {
    return __uint_as_float(u & 0xffff0000u);
}

// ------- Kernel 0: Wext = [W | W@aT | W@pT] -> bf16 h/l, FRAGMENT-MAJOR -----
// 64 blocks: all blocks zero a slice of ssum; block 0 computes the Wext tables.
__global__ __launch_bounds__(256) void k0_prep(const float* __restrict__ W,
                                               const float* __restrict__ alpha,
                                               const float* __restrict__ phi,
                                               unsigned short* __restrict__ Wh,
                                               unsigned short* __restrict__ Wl,
                                               float* __restrict__ ssum) {
    const int tid = threadIdx.x;
    {
        int i = blockIdx.x * 256 + tid;
        if (i < 12800)
            reinterpret_cast<float4*>(ssum)[i] = (float4){0.f, 0.f, 0.f, 0.f};
    }
    if (blockIdx.x != 0) return;

    __shared__ float sW[64][64];
    __shared__ float sA[32][64];   // rows 0..15 alpha, 16..31 phi
    __shared__ float sWe[64][96];
    for (int i = tid; i < 1024; i += 256)
        reinterpret_cast<float4*>(&sW[0][0])[i] = reinterpret_cast<const float4*>(W)[i];
    for (int i = tid; i < 512; i += 256) {
        float4 v = (i < 256) ? reinterpret_cast<const float4*>(alpha)[i]
                             : reinterpret_cast<const float4*>(phi)[i - 256];
        reinterpret_cast<float4*>(&sA[0][0])[i] = v;
    }
    __syncthreads();
    for (int i = tid; i < 1024; i += 256) {           // copy W -> cols 0..63
        int ci = i >> 4, q = i & 15;
        *reinterpret_cast<float4*>(&sWe[ci][4 * q]) =
            reinterpret_cast<const float4*>(&sW[ci][0])[q];
    }
    for (int i = tid; i < 2048; i += 256) {           // dots -> cols 64..95
        int ci = i >> 5, j = i & 31;
        const float4* a = reinterpret_cast<const float4*>(&sW[ci][0]);
        const float4* b = reinterpret_cast<const float4*>(&sA[j][0]);
        float acc = 0.f;
#pragma unroll
        for (int q = 0; q < 16; ++q) {
            float4 u = a[q], w = b[q];
            acc += u.x * w.x + u.y * w.y + u.z * w.z + u.w * w.w;
        }
        sWe[ci][64 + j] = acc;
    }
    __syncthreads();
    for (int i = tid; i < 6144; i += 256) {
        int k = i / 96, c = i - 96 * k;
        float f = sWe[k][c];
        unsigned short h = f2bf(f);
        int off = (((k >> 3) * 96) + c) * 8 + (k & 7);
        Wh[off] = h;
        Wl[off] = f2bf(f - bf2f(h));
    }
}

// epilogue for one finished tile, reading from sF (LDS) — no register capture
#define K1_EPILOGUE(P0)                                                          \
    {                                                                            \
        for (int i = tid; i < 1600; i += 512) {                                  \
            const int vv = i >> 6, c = i & 63;                                   \
            float s = sF[vv][c] + sF[vv + 25][c] + sF[vv + 50][c] + sF[vv + 75][c]; \
            atomicAdd(&ssum[((size_t)n * VV + vv) * CC + c], s);                 \
        }                                                                        \
        for (int i = tid; i < 1600; i += 512) {                                  \
            const int row = i >> 4, q = i & 15;                                  \
            const int tloc = row / 25, vv = row - 25 * tloc;                     \
            size_t dst = (((size_t)n * VV + vv) * TT + ((P0) + tloc)) * CC + 4 * q; \
            float4 v = *reinterpret_cast<const float4*>(&sF[row][4 * q]);        \
            ushort4 b = {f2bf(v.x), f2bf(v.y), f2bf(v.z), f2bf(v.w)};            \
            *reinterpret_cast<ushort4*>(&xwv[dst]) = b;                          \
        }                                                                        \
        if (tid < 400) {                                                         \
            const int row = tid >> 2, q = tid & 3;                               \
            const int tloc = row / 25, vv = row - 25 * tloc;                     \
            size_t dst = (((size_t)n * VV + vv) * TT + ((P0) + tloc)) * 16 + 4 * q; \
            *reinterpret_cast<float4*>(&xws2[dst]) =                             \
                *reinterpret_cast<const float4*>(&sF[row][80 + 4 * q]);          \
        }                                                                        \
        if (tid < 200) {                                                         \
            const int re = tid >> 2, q = tid & 3;                                \
            const int te = re / 25, vv = re - 25 * te;                           \
            const int tp = ((P0) + 2 * te) >> 1;                                 \
            size_t dst = (((size_t)n * VV + vv) * TPOUT + tp) * 16 + 4 * q;      \
            *reinterpret_cast<float4*>(&xws1[dst]) =                             \
                *reinterpret_cast<const float4*>(&sF[2 * te * 25 + vv][64 + 4 * q]); \
        }                                                                        \
    }

// ------- Kernel 1: 3-tile loop, store-drain pipelined -----------------------
// Per tile: {issue stage loads (regs)} -> {epilogue of PREVIOUS tile from sF:
// LDS reads + global stores} -> barrier (stores drain WITH the ~900-cyc stage
// loads, hiding the burst that was exposed at every block death in r22/r24)
// -> convert/write sA -> MFMA -> sF. Math byte-identical to r24.
__global__ __launch_bounds__(512) void k1_mfma(const float* __restrict__ x,
                                               const unsigned short* __restrict__ Bh,
                                               const unsigned short* __restrict__ Bl,
                                               unsigned short* __restrict__ xwv,
                                               float* __restrict__ xws1,
                                               float* __restrict__ xws2,
                                               float* __restrict__ ssum) {
    __shared__ __align__(16) char smem[40000];
    unsigned short (*sAh)[ALD] = reinterpret_cast<unsigned short(*)[ALD]>(smem);
    unsigned short (*sAl)[ALD] = reinterpret_cast<unsigned short(*)[ALD]>(smem + 18432);
    float (*sF)[FLD] = reinterpret_cast<float(*)[FLD]>(smem);   // barrier-separated reuse

    const int n  = blockIdx.y;
    const int tg = blockIdx.x;            // 0..24 -> tiles tg*3 .. tg*3+2
    const int tid = threadIdx.x;
    const int w    = tid >> 6;
    const int lane = tid & 63;
    const int lm   = lane & 15;
    const int g    = lane >> 4;
    const int mc   = w * 16 + lm;
    const int cig  = tid & 15, tq = tid >> 4;

#pragma unroll
    for (int it = 0; it < TPB; ++it) {
        const int t0 = (tg * TPB + it) * TC;

        // ---- stage loads FIRST (critical path; prev stores queue with them) ----
        float4 ld0, ld1, ld2, ld3;
        if (tid < 400) {
            const float* xp = x + (size_t)n * CC * TT * VV + (size_t)t0 * VV + 4 * tq;
            ld0 = *reinterpret_cast<const float4*>(&xp[(size_t)(cig * 4 + 0) * TT * VV]);
            ld1 = *reinterpret_cast<const float4*>(&xp[(size_t)(cig * 4 + 1) * TT * VV]);
            ld2 = *reinterpret_cast<const float4*>(&xp[(size_t)(cig * 4 + 2) * TT * VV]);
            ld3 = *reinterpret_cast<const float4*>(&xp[(size_t)(cig * 4 + 3) * TT * VV]);
        }

        // ---- epilogue of previous tile straight from sF ----
        if (it > 0) {
            const int p0 = (tg * TPB + it - 1) * TC;
            K1_EPILOGUE(p0);
        }
        __syncthreads();   // sF reads done; loads+stores drain together here

        // ---- convert + write sA (aliases sF — safe after barrier) ----
        if (tid < 400) {
            unsigned short mh[4][4], ml[4][4];
            float4 lds4[4] = {ld0, ld1, ld2, ld3};
#pragma unroll
            for (int u = 0; u < 4; ++u) {
                float4 v = lds4[u];
                unsigned short h0 = f2bf(v.x), h1 = f2bf(v.y), h2 = f2bf(v.z), h3 = f2bf(v.w);
                mh[0][u] = h0; mh[1][u] = h1; mh[2][u] = h2; mh[3][u] = h3;
                ml[0][u] = f2bf(v.x - bf2f(h0));
                ml[1][u] = f2bf(v.y - bf2f(h1));
                ml[2][u] = f2bf(v.z - bf2f(h2));
                ml[3][u] = f2bf(v.w - bf2f(h3));
            }
#pragma unroll
            for (int i = 0; i < 4; ++i) {
                *reinterpret_cast<uint2*>(&sAh[4 * tq + i][cig * 4]) =
                    *reinterpret_cast<const uint2*>(&mh[i][0]);
                *reinterpret_cast<uint2*>(&sAl[4 * tq + i][cig * 4]) =
                    *reinterpret_cast<const uint2*>(&ml[i][0]);
            }
        }
        __syncthreads();

        // ---- MFMA ----
        f32x4 acc[6];
#pragma unroll
        for (int b = 0; b < 6; ++b) acc[b] = (f32x4){0.f, 0.f, 0.f, 0.f};
#pragma unroll
        for (int kh = 0; kh < 2; ++kh) {
            const int kb = kh * 32 + g * 8;
            const int kc = kb >> 3;
            bf16x8 ah = *reinterpret_cast<const bf16x8*>(&sAh[mc][kb]);
            bf16x8 al = *reinterpret_cast<const bf16x8*>(&sAl[mc][kb]);
#pragma unroll
            for (int nt = 0; nt < 6; ++nt) {
                const int nc = nt * 16 + lm;
                bf16x8 bh = *reinterpret_cast<const bf16x8*>(&Bh[(size_t)(kc * 96 + nc) * 8]);
                acc[nt] = __builtin_amdgcn_mfma_f32_16x16x32_bf16(ah, bh, acc[nt], 0, 0, 0);
                if (nt >= 4) {   // score cols: h*l + l*h correction passes
                    bf16x8 bl = *reinterpret_cast<const bf16x8*>(&Bl[(size_t)(kc * 96 + nc) * 8]);
                    acc[nt] = __builtin_amdgcn_mfma_f32_16x16x32_bf16(ah, bl, acc[nt], 0, 0, 0);
                    acc[nt] = __builtin_amdgcn_mfma_f32_16x16x32_bf16(al, bh, acc[nt], 0, 0, 0);
                }
            }
        }
        __syncthreads();   // sA dead; reuse as sF

        // ---- stage accs to sF ----
#pragma unroll
        for (int j = 0; j < 4; ++j) {
            const int row = w * 16 + g * 4 + j;
            if (row < 100) {
#pragma unroll
                for (int nt = 0; nt < 6; ++nt)
                    sF[row][nt * 16 + lm] = acc[nt][j];
            }
        }
        __syncthreads();
    }

    // ---- final tile's epilogue ----
    {
        const int p0 = (tg * TPB + TPB - 1) * TC;
        K1_EPILOGUE(p0);
    }
}

// ------- Kernel 2 (fused attention + transpose): r24 proven, unchanged ------
__global__ __launch_bounds__(512) void k2_fused(const unsigned short* __restrict__ xwv,
                                                const float* __restrict__ xws1,
                                                const float* __restrict__ xws2,
                                                const float* __restrict__ ssum,
                                                float* __restrict__ out) {
    const int tpg = blockIdx.x;   // 0..29
    const int n   = blockIdx.y;   // 0..31
    const int tid = threadIdx.x;
    const int tp0 = tpg * TPG;

    __shared__ unsigned short sOut[TPG * VV][66];   // [tpl*25+v][c] bf16, pad 66
    __shared__ float sss[VV][CC];
    __shared__ float sscore[TPG][VV][9];
    __shared__ float scoef[TPG][VV][10];

    for (int i = tid; i < VV * CC; i += 512)
        (&sss[0][0])[i] = ssum[((size_t)n * VV) * CC + i];

    for (int j = tid; j < TPG * VV * 9; j += 512) {
        const int tpl = j / (VV * 9);
        const int rem = j - tpl * (VV * 9);
        const int v = rem / 9, k = rem - 9 * v;
        const int t = 2 * (tp0 + tpl);
        const int s = t - KH + k;
        float sc = 0.f;
        if (s >= 0 && s < TT) {
            const size_t r = (size_t)n * VV + v;
            const float4* x1 = reinterpret_cast<const float4*>(&xws1[(r * TPOUT + tp0 + tpl) * 16]);
            const float4* x2 = reinterpret_cast<const float4*>(&xws2[(r * TT + s) * 16]);
#pragma unroll
            for (int q = 0; q < 4; ++q) {
                float4 a = x1[q], b = x2[q];
                sc += a.x * b.x + a.y * b.y + a.z * b.z + a.w * b.w;
            }
        }
        sscore[tpl][v][k] = sc;
    }
    __syncthreads();

    for (int j = tid; j < TPG * VV; j += 512) {
        const int tpl = j / VV, v = j - tpl * VV;
        const int t = 2 * (tp0 + tpl);
        float m = 0.f;
        int nb = 0;
#pragma unroll
        for (int k = 0; k < 9; ++k) {
            int s = t - KH + k;
            if (s >= 0 && s < TT) { nb++; m = fmaxf(m, sscore[tpl][v][k]); }
        }
        float wbg = __expf(-m);
        float Z = (float)(TT - nb) * wbg;
        float e[9];
#pragma unroll
        for (int k = 0; k < 9; ++k) {
            int s = t - KH + k;
            float ek = (s >= 0 && s < TT) ? __expf(sscore[tpl][v][k] - m) : 0.f;
            e[k] = ek;
            Z += ek;
        }
        float inv = 1.f / Z;
#pragma unroll
        for (int k = 0; k < 9; ++k) {
            int s = t - KH + k;
            scoef[tpl][v][k] = (s >= 0 && s < TT) ? (e[k] - wbg) * inv : 0.f;
        }
        scoef[tpl][v][9] = wbg * inv;
    }
    __syncthreads();

    for (int j = tid; j < TPG * VV * 8; j += 512) {
        const int w  = j >> 3;              // tpl*25 + v
        const int cg = j & 7;               // c = cg*8 .. cg*8+7
        const int tpl = w / VV, v = w - tpl * VV;
        const int t = 2 * (tp0 + tpl);
        const size_t rbase = ((size_t)n * VV + v) * TT;
        const int c0 = cg * 8;

        float val[8];
        {
            const float cbg = scoef[tpl][v][9];
#pragma unroll
            for (int i = 0; i < 8; ++i) val[i] = cbg * sss[v][c0 + i];
        }
#pragma unroll
        for (int k = 0; k < 9; ++k) {
            int s = t - KH + k;
            s = min(max(s, 0), TT - 1);     // coef is 0 for invalid slots
            const float cf = scoef[tpl][v][k];
            uint4 u = *reinterpret_cast<const uint4*>(&xwv[(rbase + s) * CC + c0]);
            val[0] = fmaf(cf, bfLO(u.x), val[0]);
            val[1] = fmaf(cf, bfHI(u.x), val[1]);
            val[2] = fmaf(cf, bfLO(u.y), val[2]);
            val[3] = fmaf(cf, bfHI(u.y), val[3]);
            val[4] = fmaf(cf, bfLO(u.z), val[4]);
            val[5] = fmaf(cf, bfHI(u.z), val[5]);
            val[6] = fmaf(cf, bfLO(u.w), val[6]);
            val[7] = fmaf(cf, bfHI(u.w), val[7]);
        }
#pragma unroll
        for (int i = 0; i < 8; ++i) sOut[w][c0 + i] = f2bf(val[i]);
    }
    __syncthreads();

    float* dst = out + ((size_t)n * CC * TPOUT * VV + (size_t)tp0 * VV);
    for (int j = tid; j < CC * TPG * VV; j += 512) {
        const int c = j / (TPG * VV);
        const int w = j - c * (TPG * VV);   // tpl*25 + v
        dst[(size_t)c * (TPOUT * VV) + w] = bf2f(sOut[w][c]);
    }
}

extern "C" void kernel_launch(void* const* d_in, const int* in_sizes, int n_in,
                              void* d_out, int out_size, void* d_ws, size_t ws_size,
                              hipStream_t stream) {
    const float* x     = (const float*)d_in[0];
    const float* W     = (const float*)d_in[1];
    const float* alpha = (const float*)d_in[2];
    const float* phi   = (const float*)d_in[3];
    float* out = (float*)d_out;

    float* xws2 = (float*)d_ws;                           // 800*300*16 f32 = 15.4 MB
    float* xws1 = xws2 + (size_t)800 * 300 * 16;          // 800*150*16 f32 =  7.7 MB
    float* ssum = xws1 + (size_t)800 * 150 * 16;          // 800*64 f32
    unsigned short* xwv = (unsigned short*)(ssum + (size_t)800 * 64);  // 30.7 MB
    unsigned short* Wh  = xwv + (size_t)800 * 300 * CC;   // 6144 u16
    unsigned short* Wl  = Wh + 6144;                      // 6144 u16 (~54 MB total)

    k0_prep<<<64, 256, 0, stream>>>(W, alpha, phi, Wh, Wl, ssum);
    dim3 g1(TT / (TC * TPB), NB);                         // 25 x 32 = 800 blocks
    k1_mfma<<<g1, 512, 0, stream>>>(x, Wh, Wl, xwv, xws1, xws2, ssum);
    dim3 g2(TPOUT / TPG, NB);
    k2_fused<<<g2, 512, 0, stream>>>(xwv, xws1, xws2, ssum, out);
}

// Round 26
// 68.758 us; speedup vs baseline: 1.1685x; 1.1685x over previous
//
#include <hip/hip_runtime.h>

#define NB 32
#define CC 64
#define TT 300
#define VV 25
#define HH 16
#define TPOUT 150
#define KH 4       // kernel//2
#define TC 4       // timesteps per k1 tile
#define TPG 5      // tp per fused-k2 block

#define ALD 72     // sA row stride in u16 (144 B, 16B-aligned; b128 reads 2-way free)
#define FLD 100    // sF row stride in f32

typedef __attribute__((ext_vector_type(4))) float f32x4;
typedef __attribute__((ext_vector_type(8))) short bf16x8;

static __device__ __forceinline__ unsigned short f2bf(float f) {
    unsigned u = __float_as_uint(f);
    unsigned r = (u + 0x7FFFu + ((u >> 16) & 1u)) >> 16;   // RNE
    return (unsigned short)r;
}
static __device__ __forceinline__ float bf2f(unsigned short h) {
    return __uint_as_float(((unsigned)h) << 16);
}
static __device__ __forceinline__ float bfLO(unsigned u) {
    return __uint_as_float(u << 16);
}
static __device__ __forceinline__ float bfHI(unsigned u) {
    return __uint_as_float(u & 0xffff0000u);
}

// ------- Kernel 0: Wext = [W | W@aT | W@pT] -> bf16 h/l, FRAGMENT-MAJOR -----
// 64 blocks: all blocks zero a slice of ssum; block 0 computes the Wext tables.
__global__ __launch_bounds__(256) void k0_prep(const float* __restrict__ W,
                                               const float* __restrict__ alpha,
                                               const float* __restrict__ phi,
                                               unsigned short* __restrict__ Wh,
                                               unsigned short* __restrict__ Wl,
                                               float* __restrict__ ssum) {
    const int tid = threadIdx.x;
    {
        int i = blockIdx.x * 256 + tid;
        if (i < 12800)
            reinterpret_cast<float4*>(ssum)[i] = (float4){0.f, 0.f, 0.f, 0.f};
    }
    if (blockIdx.x != 0) return;

    __shared__ float sW[64][64];
    __shared__ float sA[32][64];   // rows 0..15 alpha, 16..31 phi
    __shared__ float sWe[64][96];
    for (int i = tid; i < 1024; i += 256)
        reinterpret_cast<float4*>(&sW[0][0])[i] = reinterpret_cast<const float4*>(W)[i];
    for (int i = tid; i < 512; i += 256) {
        float4 v = (i < 256) ? reinterpret_cast<const float4*>(alpha)[i]
                             : reinterpret_cast<const float4*>(phi)[i - 256];
        reinterpret_cast<float4*>(&sA[0][0])[i] = v;
    }
    __syncthreads();
    for (int i = tid; i < 1024; i += 256) {           // copy W -> cols 0..63
        int ci = i >> 4, q = i & 15;
        *reinterpret_cast<float4*>(&sWe[ci][4 * q]) =
            reinterpret_cast<const float4*>(&sW[ci][0])[q];
    }
    for (int i = tid; i < 2048; i += 256) {           // dots -> cols 64..95
        int ci = i >> 5, j = i & 31;
        const float4* a = reinterpret_cast<const float4*>(&sW[ci][0]);
        const float4* b = reinterpret_cast<const float4*>(&sA[j][0]);
        float acc = 0.f;
#pragma unroll
        for (int q = 0; q < 16; ++q) {
            float4 u = a[q], w = b[q];
            acc += u.x * w.x + u.y * w.y + u.z * w.z + u.w * w.w;
        }
        sWe[ci][64 + j] = acc;
    }
    __syncthreads();
    for (int i = tid; i < 6144; i += 256) {
        int k = i / 96, c = i - 96 * k;
        float f = sWe[k][c];
        unsigned short h = f2bf(f);
        int off = (((k >> 3) * 96) + c) * 8 + (k & 7);
        Wh[off] = h;
        Wl[off] = f2bf(f - bf2f(h));
    }
}

// ------- Kernel 1: xwv(bf16)/xws1,xws2(f32) via bf16 MFMA + fused colsum ----
// r22 proven structure. Score cols split: x2 (cols 80..95 of sF) stored for
// ALL rows; x1 (cols 64..79) only for EVEN t (the selected rows) — x1 at odd
// t was never consumed.
__global__ __launch_bounds__(512) void k1_mfma(const float* __restrict__ x,
                                               const unsigned short* __restrict__ Bh,
                                               const unsigned short* __restrict__ Bl,
                                               unsigned short* __restrict__ xwv,
                                               float* __restrict__ xws1,
                                               float* __restrict__ xws2,
                                               float* __restrict__ ssum) {
    __shared__ __align__(16) char smem[40000];
    unsigned short (*sAh)[ALD] = reinterpret_cast<unsigned short(*)[ALD]>(smem);
    unsigned short (*sAl)[ALD] = reinterpret_cast<unsigned short(*)[ALD]>(smem + 18432);
    float (*sF)[FLD] = reinterpret_cast<float(*)[FLD]>(smem);   // barrier-separated reuse

    const int n  = blockIdx.y;
    const int t0 = blockIdx.x * TC;
    const int tid = threadIdx.x;

    if (tid < 400) {
        const int cig = tid & 15, tq = tid >> 4;      // tq 0..24
        const float* xp = x + (size_t)n * CC * TT * VV + (size_t)t0 * VV + 4 * tq;
        unsigned short mh[4][4], ml[4][4];
#pragma unroll
        for (int u = 0; u < 4; ++u) {
            const int ci = cig * 4 + u;
            float4 v = *reinterpret_cast<const float4*>(&xp[(size_t)ci * TT * VV]);
            unsigned short h0 = f2bf(v.x), h1 = f2bf(v.y), h2 = f2bf(v.z), h3 = f2bf(v.w);
            mh[0][u] = h0; mh[1][u] = h1; mh[2][u] = h2; mh[3][u] = h3;
            ml[0][u] = f2bf(v.x - bf2f(h0));
            ml[1][u] = f2bf(v.y - bf2f(h1));
            ml[2][u] = f2bf(v.z - bf2f(h2));
            ml[3][u] = f2bf(v.w - bf2f(h3));
        }
#pragma unroll
        for (int i = 0; i < 4; ++i) {
            *reinterpret_cast<uint2*>(&sAh[4 * tq + i][cig * 4]) =
                *reinterpret_cast<const uint2*>(&mh[i][0]);
            *reinterpret_cast<uint2*>(&sAl[4 * tq + i][cig * 4]) =
                *reinterpret_cast<const uint2*>(&ml[i][0]);
        }
    }
    __syncthreads();

    const int w    = tid >> 6;        // wave = M-tile 0..7
    const int lane = tid & 63;
    const int lm   = lane & 15;
    const int g    = lane >> 4;
    const int mc   = w * 16 + lm;

    f32x4 acc[6];
#pragma unroll
    for (int b = 0; b < 6; ++b) acc[b] = (f32x4){0.f, 0.f, 0.f, 0.f};

#pragma unroll
    for (int kh = 0; kh < 2; ++kh) {
        const int kb = kh * 32 + g * 8;
        const int kc = kb >> 3;
        bf16x8 ah = *reinterpret_cast<const bf16x8*>(&sAh[mc][kb]);
        bf16x8 al = *reinterpret_cast<const bf16x8*>(&sAl[mc][kb]);
#pragma unroll
        for (int nt = 0; nt < 6; ++nt) {
            const int nc = nt * 16 + lm;
            bf16x8 bh = *reinterpret_cast<const bf16x8*>(&Bh[(size_t)(kc * 96 + nc) * 8]);
            acc[nt] = __builtin_amdgcn_mfma_f32_16x16x32_bf16(ah, bh, acc[nt], 0, 0, 0);
            if (nt >= 4) {   // score cols: h*l + l*h correction passes
                bf16x8 bl = *reinterpret_cast<const bf16x8*>(&Bl[(size_t)(kc * 96 + nc) * 8]);
                acc[nt] = __builtin_amdgcn_mfma_f32_16x16x32_bf16(ah, bl, acc[nt], 0, 0, 0);
                acc[nt] = __builtin_amdgcn_mfma_f32_16x16x32_bf16(al, bh, acc[nt], 0, 0, 0);
            }
        }
    }
    __syncthreads();   // sA dead; reuse as sF

#pragma unroll
    for (int j = 0; j < 4; ++j) {
        const int row = w * 16 + g * 4 + j;
        if (row < 100) {
#pragma unroll
            for (int nt = 0; nt < 6; ++nt)
                sF[row][nt * 16 + lm] = acc[nt][j];
        }
    }
    __syncthreads();

    // ---- column partials -> ssum (f32 exact, pre-quantization) ----
    for (int i = tid; i < 1600; i += 512) {
        const int vv = i >> 6, c = i & 63;
        float s = sF[vv][c] + sF[vv + 25][c] + sF[vv + 50][c] + sF[vv + 75][c];
        atomicAdd(&ssum[((size_t)n * VV + vv) * CC + c], s);
    }
    // ---- xwv stores: bf16, 128 B contiguous per row ----
    for (int i = tid; i < 1600; i += 512) {
        const int row = i >> 4, q = i & 15;
        const int tloc = row / 25, vv = row - 25 * tloc;
        size_t dst = (((size_t)n * VV + vv) * TT + (t0 + tloc)) * CC + 4 * q;
        float4 v = *reinterpret_cast<const float4*>(&sF[row][4 * q]);
        ushort4 b = {f2bf(v.x), f2bf(v.y), f2bf(v.z), f2bf(v.w)};
        *reinterpret_cast<ushort4*>(&xwv[dst]) = b;
    }
    // ---- xws2 (x2) stores: all 100 rows, 400 float4 jobs ----
    if (tid < 400) {
        const int row = tid >> 2, q = tid & 3;
        const int tloc = row / 25, vv = row - 25 * tloc;
        size_t dst = (((size_t)n * VV + vv) * TT + (t0 + tloc)) * 16 + 4 * q;
        *reinterpret_cast<float4*>(&xws2[dst]) =
            *reinterpret_cast<const float4*>(&sF[row][80 + 4 * q]);
    }
    // ---- xws1 (x1) stores: EVEN rows only (t0 is even, so tloc in {0,2}) ----
    if (tid < 200) {
        const int re = tid >> 2, q = tid & 3;     // re 0..49
        const int te = re / 25, vv = re - 25 * te;  // te 0..1 -> tloc = 2*te
        const int tp = (t0 + 2 * te) >> 1;
        size_t dst = (((size_t)n * VV + vv) * TPOUT + tp) * 16 + 4 * q;
        *reinterpret_cast<float4*>(&xws1[dst]) =
            *reinterpret_cast<const float4*>(&sF[2 * te * 25 + vv][64 + 4 * q]);
    }
}

// ------- Kernel 2 (fused attention + transpose): one (tp-group, n) block ----
// sOut in bf16 (rounding proven at absmax 0.03125) -> LDS ~32 KB -> 4
// blocks/CU -> 1024 resident >= 960 blocks = single dispatch wave.
// 9-tap accumulation: one thread per (w, 8-c group) -> each tap is ONE 16 B
// uint4 load + 8 single-op bf16 decodes. Store writes out[n][c][tp][v]
// directly in 500 B contiguous runs (transpose via padded LDS).
__global__ __launch_bounds__(512) void k2_fused(const unsigned short* __restrict__ xwv,
                                                const float* __restrict__ xws1,
                                                const float* __restrict__ xws2,
                                                const float* __restrict__ ssum,
                                                float* __restrict__ out) {
    const int tpg = blockIdx.x;   // 0..29
    const int n   = blockIdx.y;   // 0..31
    const int tid = threadIdx.x;
    const int tp0 = tpg * TPG;

    __shared__ unsigned short sOut[TPG * VV][66];   // [tpl*25+v][c] bf16, pad 66
    __shared__ float sss[VV][CC];
    __shared__ float sscore[TPG][VV][9];
    __shared__ float scoef[TPG][VV][10];

    for (int i = tid; i < VV * CC; i += 512)
        (&sss[0][0])[i] = ssum[((size_t)n * VV) * CC + i];

    // ---- scores: x1 from xws1 (even-row table), x2 from xws2 ----
    for (int j = tid; j < TPG * VV * 9; j += 512) {
        const int tpl = j / (VV * 9);
        const int rem = j - tpl * (VV * 9);
        const int v = rem / 9, k = rem - 9 * v;
        const int t = 2 * (tp0 + tpl);
        const int s = t - KH + k;
        float sc = 0.f;
        if (s >= 0 && s < TT) {
            const size_t r = (size_t)n * VV + v;
            const float4* x1 = reinterpret_cast<const float4*>(&xws1[(r * TPOUT + tp0 + tpl) * 16]);
            const float4* x2 = reinterpret_cast<const float4*>(&xws2[(r * TT + s) * 16]);
#pragma unroll
            for (int q = 0; q < 4; ++q) {
                float4 a = x1[q], b = x2[q];
                sc += a.x * b.x + a.y * b.y + a.z * b.z + a.w * b.w;
            }
        }
        sscore[tpl][v][k] = sc;
    }
    __syncthreads();

    // ---- softmax coefficients: 125 (tpl, v) jobs ----
    for (int j = tid; j < TPG * VV; j += 512) {
        const int tpl = j / VV, v = j - tpl * VV;
        const int t = 2 * (tp0 + tpl);
        float m = 0.f;
        int nb = 0;
#pragma unroll
        for (int k = 0; k < 9; ++k) {
            int s = t - KH + k;
            if (s >= 0 && s < TT) { nb++; m = fmaxf(m, sscore[tpl][v][k]); }
        }
        float wbg = __expf(-m);
        float Z = (float)(TT - nb) * wbg;
        float e[9];
#pragma unroll
        for (int k = 0; k < 9; ++k) {
            int s = t - KH + k;
            float ek = (s >= 0 && s < TT) ? __expf(sscore[tpl][v][k] - m) : 0.f;
            e[k] = ek;
            Z += ek;
        }
        float inv = 1.f / Z;
#pragma unroll
        for (int k = 0; k < 9; ++k) {
            int s = t - KH + k;
            scoef[tpl][v][k] = (s >= 0 && s < TT) ? (e[k] - wbg) * inv : 0.f;
        }
        scoef[tpl][v][9] = wbg * inv;
    }
    __syncthreads();

    // ---- 9-tap accumulation: thread = (w, 8-c group); uint4 tap loads ----
    for (int j = tid; j < TPG * VV * 8; j += 512) {
        const int w  = j >> 3;              // tpl*25 + v
        const int cg = j & 7;               // c = cg*8 .. cg*8+7
        const int tpl = w / VV, v = w - tpl * VV;
        const int t = 2 * (tp0 + tpl);
        const size_t rbase = ((size_t)n * VV + v) * TT;
        const int c0 = cg * 8;

        float val[8];
        {
            const float cbg = scoef[tpl][v][9];
#pragma unroll
            for (int i = 0; i < 8; ++i) val[i] = cbg * sss[v][c0 + i];
        }
#pragma unroll
        for (int k = 0; k < 9; ++k) {
            int s = t - KH + k;
            s = min(max(s, 0), TT - 1);     // coef is 0 for invalid slots
            const float cf = scoef[tpl][v][k];
            uint4 u = *reinterpret_cast<const uint4*>(&xwv[(rbase + s) * CC + c0]);
            val[0] = fmaf(cf, bfLO(u.x), val[0]);
            val[1] = fmaf(cf, bfHI(u.x), val[1]);
            val[2] = fmaf(cf, bfLO(u.y), val[2]);
            val[3] = fmaf(cf, bfHI(u.y), val[3]);
            val[4] = fmaf(cf, bfLO(u.z), val[4]);
            val[5] = fmaf(cf, bfHI(u.z), val[5]);
            val[6] = fmaf(cf, bfLO(u.w), val[6]);
            val[7] = fmaf(cf, bfHI(u.w), val[7]);
        }
#pragma unroll
        for (int i = 0; i < 8; ++i) sOut[w][c0 + i] = f2bf(val[i]);
    }
    __syncthreads();

    // ---- store: v-major, 125 contiguous floats (500 B) per c ----
    float* dst = out + ((size_t)n * CC * TPOUT * VV + (size_t)tp0 * VV);
    for (int j = tid; j < CC * TPG * VV; j += 512) {
        const int c = j / (TPG * VV);
        const int w = j - c * (TPG * VV);   // tpl*25 + v
        dst[(size_t)c * (TPOUT * VV) + w] = bf2f(sOut[w][c]);
    }
}

extern "C" void kernel_launch(void* const* d_in, const int* in_sizes, int n_in,
                              void* d_out, int out_size, void* d_ws, size_t ws_size,
                              hipStream_t stream) {
    const float* x     = (const float*)d_in[0];
    const float* W     = (const float*)d_in[1];
    const float* alpha = (const float*)d_in[2];
    const float* phi   = (const float*)d_in[3];
    float* out = (float*)d_out;

    float* xws2 = (float*)d_ws;                           // 800*300*16 f32 = 15.4 MB
    float* xws1 = xws2 + (size_t)800 * 300 * 16;          // 800*150*16 f32 =  7.7 MB
    float* ssum = xws1 + (size_t)800 * 150 * 16;          // 800*64 f32
    unsigned short* xwv = (unsigned short*)(ssum + (size_t)800 * 64);  // 30.7 MB
    unsigned short* Wh  = xwv + (size_t)800 * 300 * CC;   // 6144 u16
    unsigned short* Wl  = Wh + 6144;                      // 6144 u16 (~54 MB total)

    k0_prep<<<64, 256, 0, stream>>>(W, alpha, phi, Wh, Wl, ssum);
    dim3 g1(TT / TC, NB);
    k1_mfma<<<g1, 512, 0, stream>>>(x, Wh, Wl, xwv, xws1, xws2, ssum);
    dim3 g2(TPOUT / TPG, NB);
    k2_fused<<<g2, 512, 0, stream>>>(xwv, xws1, xws2, ssum, out);
}

// Round 27
// 66.968 us; speedup vs baseline: 1.1997x; 1.0267x over previous
//
#include <hip/hip_runtime.h>

#define NB 32
#define CC 64
#define TT 300
#define VV 25
#define HH 16
#define TPOUT 150
#define KH 4       // kernel//2
#define TC 4       // timesteps per k1 tile
#define TPB 3      // tiles per k1 block (plain rolled loop, no reg carrying)
#define TPG 5      // tp per fused-k2 block

#define ALD 72     // sA row stride in u16 (144 B, 16B-aligned; b128 reads 2-way free)
#define FLD 100    // sF row stride in f32

typedef __attribute__((ext_vector_type(4))) float f32x4;
typedef __attribute__((ext_vector_type(8))) short bf16x8;

static __device__ __forceinline__ unsigned short f2bf(float f) {
    unsigned u = __float_as_uint(f);
    unsigned r = (u + 0x7FFFu + ((u >> 16) & 1u)) >> 16;   // RNE
    return (unsigned short)r;
}
static __device__ __forceinline__ float bf2f(unsigned short h) {
    return __uint_as_float(((unsigned)h) << 16);
}
static __device__ __forceinline__ float bfLO(unsigned u) {
    return __uint_as_float(u << 16);
}
static __device__ __forceinline__ float bfHI(unsigned u) {
    return __uint_as_float(u & 0xffff0000u);
}

// ------- Kernel 0: Wext = [W | W@aT | W@pT] -> bf16 h/l, FRAGMENT-MAJOR -----
// 64 blocks: all blocks zero a slice of ssum; block 0 computes the Wext tables.
__global__ __launch_bounds__(256) void k0_prep(const float* __restrict__ W,
                                               const float* __restrict__ alpha,
                                               const float* __restrict__ phi,
                                               unsigned short* __restrict__ Wh,
                                               unsigned short* __restrict__ Wl,
                                               float* __restrict__ ssum) {
    const int tid = threadIdx.x;
    {
        int i = blockIdx.x * 256 + tid;
        if (i < 12800)
            reinterpret_cast<float4*>(ssum)[i] = (float4){0.f, 0.f, 0.f, 0.f};
    }
    if (blockIdx.x != 0) return;

    __shared__ float sW[64][64];
    __shared__ float sA[32][64];   // rows 0..15 alpha, 16..31 phi
    __shared__ float sWe[64][96];
    for (int i = tid; i < 1024; i += 256)
        reinterpret_cast<float4*>(&sW[0][0])[i] = reinterpret_cast<const float4*>(W)[i];
    for (int i = tid; i < 512; i += 256) {
        float4 v = (i < 256) ? reinterpret_cast<const float4*>(alpha)[i]
                             : reinterpret_cast<const float4*>(phi)[i - 256];
        reinterpret_cast<float4*>(&sA[0][0])[i] = v;
    }
    __syncthreads();
    for (int i = tid; i < 1024; i += 256) {           // copy W -> cols 0..63
        int ci = i >> 4, q = i & 15;
        *reinterpret_cast<float4*>(&sWe[ci][4 * q]) =
            reinterpret_cast<const float4*>(&sW[ci][0])[q];
    }
    for (int i = tid; i < 2048; i += 256) {           // dots -> cols 64..95
        int ci = i >> 5, j = i & 31;
        const float4* a = reinterpret_cast<const float4*>(&sW[ci][0]);
        const float4* b = reinterpret_cast<const float4*>(&sA[j][0]);
        float acc = 0.f;
#pragma unroll
        for (int q = 0; q < 16; ++q) {
            float4 u = a[q], w = b[q];
            acc += u.x * w.x + u.y * w.y + u.z * w.z + u.w * w.w;
        }
        sWe[ci][64 + j] = acc;
    }
    __syncthreads();
    for (int i = tid; i < 6144; i += 256) {
        int k = i / 96, c = i - 96 * k;
        float f = sWe[k][c];
        unsigned short h = f2bf(f);
        int off = (((k >> 3) * 96) + c) * 8 + (k & 7);
        Wh[off] = h;
        Wl[off] = f2bf(f - bf2f(h));
    }
}

// ------- Kernel 1: xwv(bf16)/xws1,xws2(f32) via bf16 MFMA + fused colsum ----
// r24 proven body, looped over TPB=3 consecutive tiles per block (plain
// rolled loop, no cross-iteration register carrying -> VGPR stays ~30).
// Grid 25x32 = 800 blocks < 1024 residency cap = SINGLE dispatch wave
// (r24's 2400 blocks ran 2.34 rounds with a 34%-fill tail round).
__global__ __launch_bounds__(512) void k1_mfma(const float* __restrict__ x,
                                               const unsigned short* __restrict__ Bh,
                                               const unsigned short* __restrict__ Bl,
                                               unsigned short* __restrict__ xwv,
                                               float* __restrict__ xws1,
                                               float* __restrict__ xws2,
                                               float* __restrict__ ssum) {
    __shared__ __align__(16) char smem[40000];
    unsigned short (*sAh)[ALD] = reinterpret_cast<unsigned short(*)[ALD]>(smem);
    unsigned short (*sAl)[ALD] = reinterpret_cast<unsigned short(*)[ALD]>(smem + 18432);
    float (*sF)[FLD] = reinterpret_cast<float(*)[FLD]>(smem);   // barrier-separated reuse

    const int n  = blockIdx.y;
    const int tg = blockIdx.x;            // 0..24 -> tiles tg*3 .. tg*3+2
    const int tid = threadIdx.x;
    const int w    = tid >> 6;            // wave = M-tile 0..7
    const int lane = tid & 63;
    const int lm   = lane & 15;
    const int g    = lane >> 4;
    const int mc   = w * 16 + lm;
    const int cig  = tid & 15, tq = tid >> 4;

#pragma unroll 1
    for (int it = 0; it < TPB; ++it) {
        const int t0 = (tg * TPB + it) * TC;

        // ---- stage A: thread (tq, cig) loads 4 ci x 4 tv, packs, writes uint2 ----
        if (tid < 400) {
            const float* xp = x + (size_t)n * CC * TT * VV + (size_t)t0 * VV + 4 * tq;
            unsigned short mh[4][4], ml[4][4];
#pragma unroll
            for (int u = 0; u < 4; ++u) {
                const int ci = cig * 4 + u;
                float4 v = *reinterpret_cast<const float4*>(&xp[(size_t)ci * TT * VV]);
                unsigned short h0 = f2bf(v.x), h1 = f2bf(v.y), h2 = f2bf(v.z), h3 = f2bf(v.w);
                mh[0][u] = h0; mh[1][u] = h1; mh[2][u] = h2; mh[3][u] = h3;
                ml[0][u] = f2bf(v.x - bf2f(h0));
                ml[1][u] = f2bf(v.y - bf2f(h1));
                ml[2][u] = f2bf(v.z - bf2f(h2));
                ml[3][u] = f2bf(v.w - bf2f(h3));
            }
#pragma unroll
            for (int i = 0; i < 4; ++i) {
                *reinterpret_cast<uint2*>(&sAh[4 * tq + i][cig * 4]) =
                    *reinterpret_cast<const uint2*>(&mh[i][0]);
                *reinterpret_cast<uint2*>(&sAl[4 * tq + i][cig * 4]) =
                    *reinterpret_cast<const uint2*>(&ml[i][0]);
            }
        }
        __syncthreads();

        // ---- MFMA ----
        f32x4 acc[6];
#pragma unroll
        for (int b = 0; b < 6; ++b) acc[b] = (f32x4){0.f, 0.f, 0.f, 0.f};
#pragma unroll
        for (int kh = 0; kh < 2; ++kh) {
            const int kb = kh * 32 + g * 8;
            const int kc = kb >> 3;
            bf16x8 ah = *reinterpret_cast<const bf16x8*>(&sAh[mc][kb]);
            bf16x8 al = *reinterpret_cast<const bf16x8*>(&sAl[mc][kb]);
#pragma unroll
            for (int nt = 0; nt < 6; ++nt) {
                const int nc = nt * 16 + lm;
                bf16x8 bh = *reinterpret_cast<const bf16x8*>(&Bh[(size_t)(kc * 96 + nc) * 8]);
                acc[nt] = __builtin_amdgcn_mfma_f32_16x16x32_bf16(ah, bh, acc[nt], 0, 0, 0);
                if (nt >= 4) {   // score cols: h*l + l*h correction passes
                    bf16x8 bl = *reinterpret_cast<const bf16x8*>(&Bl[(size_t)(kc * 96 + nc) * 8]);
                    acc[nt] = __builtin_amdgcn_mfma_f32_16x16x32_bf16(ah, bl, acc[nt], 0, 0, 0);
                    acc[nt] = __builtin_amdgcn_mfma_f32_16x16x32_bf16(al, bh, acc[nt], 0, 0, 0);
                }
            }
        }
        __syncthreads();   // sA dead; reuse as sF

        // ---- stage accs to sF ----
#pragma unroll
        for (int j = 0; j < 4; ++j) {
            const int row = w * 16 + g * 4 + j;
            if (row < 100) {
#pragma unroll
                for (int nt = 0; nt < 6; ++nt)
                    sF[row][nt * 16 + lm] = acc[nt][j];
            }
        }
        __syncthreads();

        // ---- epilogue: colsum atomics + xwv bf16 + xws2/xws1 stores ----
        for (int i = tid; i < 1600; i += 512) {
            const int vv = i >> 6, c = i & 63;
            float s = sF[vv][c] + sF[vv + 25][c] + sF[vv + 50][c] + sF[vv + 75][c];
            atomicAdd(&ssum[((size_t)n * VV + vv) * CC + c], s);
        }
        for (int i = tid; i < 1600; i += 512) {
            const int row = i >> 4, q = i & 15;
            const int tloc = row / 25, vv = row - 25 * tloc;
            size_t dst = (((size_t)n * VV + vv) * TT + (t0 + tloc)) * CC + 4 * q;
            float4 v = *reinterpret_cast<const float4*>(&sF[row][4 * q]);
            ushort4 b = {f2bf(v.x), f2bf(v.y), f2bf(v.z), f2bf(v.w)};
            *reinterpret_cast<ushort4*>(&xwv[dst]) = b;
        }
        if (tid < 400) {
            const int row = tid >> 2, q = tid & 3;
            const int tloc = row / 25, vv = row - 25 * tloc;
            size_t dst = (((size_t)n * VV + vv) * TT + (t0 + tloc)) * 16 + 4 * q;
            *reinterpret_cast<float4*>(&xws2[dst]) =
                *reinterpret_cast<const float4*>(&sF[row][80 + 4 * q]);
        }
        if (tid < 200) {
            const int re = tid >> 2, q = tid & 3;       // re 0..49
            const int te = re / 25, vv = re - 25 * te;  // te 0..1 -> tloc = 2*te
            const int tp = (t0 + 2 * te) >> 1;
            size_t dst = (((size_t)n * VV + vv) * TPOUT + tp) * 16 + 4 * q;
            *reinterpret_cast<float4*>(&xws1[dst]) =
                *reinterpret_cast<const float4*>(&sF[2 * te * 25 + vv][64 + 4 * q]);
        }
        __syncthreads();   // sF reads done -> sA writable next iteration
    }
}

// ------- Kernel 2 (fused attention + transpose): r24 proven, unchanged ------
// sOut in bf16 -> LDS ~32 KB -> 4 blocks/CU -> single dispatch wave.
// 9-tap accumulation: one thread per (w, 8-c group); uint4 tap loads.
__global__ __launch_bounds__(512) void k2_fused(const unsigned short* __restrict__ xwv,
                                                const float* __restrict__ xws1,
                                                const float* __restrict__ xws2,
                                                const float* __restrict__ ssum,
                                                float* __restrict__ out) {
    const int tpg = blockIdx.x;   // 0..29
    const int n   = blockIdx.y;   // 0..31
    const int tid = threadIdx.x;
    const int tp0 = tpg * TPG;

    __shared__ unsigned short sOut[TPG * VV][66];   // [tpl*25+v][c] bf16, pad 66
    __shared__ float sss[VV][CC];
    __shared__ float sscore[TPG][VV][9];
    __shared__ float scoef[TPG][VV][10];

    for (int i = tid; i < VV * CC; i += 512)
        (&sss[0][0])[i] = ssum[((size_t)n * VV) * CC + i];

    // ---- scores: x1 from xws1 (even-row table), x2 from xws2 ----
    for (int j = tid; j < TPG * VV * 9; j += 512) {
        const int tpl = j / (VV * 9);
        const int rem = j - tpl * (VV * 9);
        const int v = rem / 9, k = rem - 9 * v;
        const int t = 2 * (tp0 + tpl);
        const int s = t - KH + k;
        float sc = 0.f;
        if (s >= 0 && s < TT) {
            const size_t r = (size_t)n * VV + v;
            const float4* x1 = reinterpret_cast<const float4*>(&xws1[(r * TPOUT + tp0 + tpl) * 16]);
            const float4* x2 = reinterpret_cast<const float4*>(&xws2[(r * TT + s) * 16]);
#pragma unroll
            for (int q = 0; q < 4; ++q) {
                float4 a = x1[q], b = x2[q];
                sc += a.x * b.x + a.y * b.y + a.z * b.z + a.w * b.w;
            }
        }
        sscore[tpl][v][k] = sc;
    }
    __syncthreads();

    // ---- softmax coefficients: 125 (tpl, v) jobs ----
    for (int j = tid; j < TPG * VV; j += 512) {
        const int tpl = j / VV, v = j - tpl * VV;
        const int t = 2 * (tp0 + tpl);
        float m = 0.f;
        int nb = 0;
#pragma unroll
        for (int k = 0; k < 9; ++k) {
            int s = t - KH + k;
            if (s >= 0 && s < TT) { nb++; m = fmaxf(m, sscore[tpl][v][k]); }
        }
        float wbg = __expf(-m);
        float Z = (float)(TT - nb) * wbg;
        float e[9];
#pragma unroll
        for (int k = 0; k < 9; ++k) {
            int s = t - KH + k;
            float ek = (s >= 0 && s < TT) ? __expf(sscore[tpl][v][k] - m) : 0.f;
            e[k] = ek;
            Z += ek;
        }
        float inv = 1.f / Z;
#pragma unroll
        for (int k = 0; k < 9; ++k) {
            int s = t - KH + k;
            scoef[tpl][v][k] = (s >= 0 && s < TT) ? (e[k] - wbg) * inv : 0.f;
        }
        scoef[tpl][v][9] = wbg * inv;
    }
    __syncthreads();

    // ---- 9-tap accumulation: thread = (w, 8-c group); uint4 tap loads ----
    for (int j = tid; j < TPG * VV * 8; j += 512) {
        const int w  = j >> 3;              // tpl*25 + v
        const int cg = j & 7;               // c = cg*8 .. cg*8+7
        const int tpl = w / VV, v = w - tpl * VV;
        const int t = 2 * (tp0 + tpl);
        const size_t rbase = ((size_t)n * VV + v) * TT;
        const int c0 = cg * 8;

        float val[8];
        {
            const float cbg = scoef[tpl][v][9];
#pragma unroll
            for (int i = 0; i < 8; ++i) val[i] = cbg * sss[v][c0 + i];
        }
#pragma unroll
        for (int k = 0; k < 9; ++k) {
            int s = t - KH + k;
            s = min(max(s, 0), TT - 1);     // coef is 0 for invalid slots
            const float cf = scoef[tpl][v][k];
            uint4 u = *reinterpret_cast<const uint4*>(&xwv[(rbase + s) * CC + c0]);
            val[0] = fmaf(cf, bfLO(u.x), val[0]);
            val[1] = fmaf(cf, bfHI(u.x), val[1]);
            val[2] = fmaf(cf, bfLO(u.y), val[2]);
            val[3] = fmaf(cf, bfHI(u.y), val[3]);
            val[4] = fmaf(cf, bfLO(u.z), val[4]);
            val[5] = fmaf(cf, bfHI(u.z), val[5]);
            val[6] = fmaf(cf, bfLO(u.w), val[6]);
            val[7] = fmaf(cf, bfHI(u.w), val[7]);
        }
#pragma unroll
        for (int i = 0; i < 8; ++i) sOut[w][c0 + i] = f2bf(val[i]);
    }
    __syncthreads();

    // ---- store: v-major, 125 contiguous floats (500 B) per c ----
    float* dst = out + ((size_t)n * CC * TPOUT * VV + (size_t)tp0 * VV);
    for (int j = tid; j < CC * TPG * VV; j += 512) {
        const int c = j / (TPG * VV);
        const int w = j - c * (TPG * VV);   // tpl*25 + v
        dst[(size_t)c * (TPOUT * VV) + w] = bf2f(sOut[w][c]);
    }
}

extern "C" void kernel_launch(void* const* d_in, const int* in_sizes, int n_in,
                              void* d_out, int out_size, void* d_ws, size_t ws_size,
                              hipStream_t stream) {
    const float* x     = (const float*)d_in[0];
    const float* W     = (const float*)d_in[1];
    const float* alpha = (const float*)d_in[2];
    const float* phi   = (const float*)d_in[3];
    float* out = (float*)d_out;

    float* xws2 = (float*)d_ws;                           // 800*300*16 f32 = 15.4 MB
    float* xws1 = xws2 + (size_t)800 * 300 * 16;          // 800*150*16 f32 =  7.7 MB
    float* ssum = xws1 + (size_t)800 * 150 * 16;          // 800*64 f32
    unsigned short* xwv = (unsigned short*)(ssum + (size_t)800 * 64);  // 30.7 MB
    unsigned short* Wh  = xwv + (size_t)800 * 300 * CC;   // 6144 u16
    unsigned short* Wl  = Wh + 6144;                      // 6144 u16 (~54 MB total)

    k0_prep<<<64, 256, 0, stream>>>(W, alpha, phi, Wh, Wl, ssum);
    dim3 g1(TT / (TC * TPB), NB);                         // 25 x 32 = 800 blocks
    k1_mfma<<<g1, 512, 0, stream>>>(x, Wh, Wl, xwv, xws1, xws2, ssum);
    dim3 g2(TPOUT / TPG, NB);
    k2_fused<<<g2, 512, 0, stream>>>(xwv, xws1, xws2, ssum, out);
}

// Round 28
// 62.752 us; speedup vs baseline: 1.2804x; 1.0672x over previous
//
#include <hip/hip_runtime.h>

#define NB 32
#define CC 64
#define TT 300
#define VV 25
#define HH 16
#define TPOUT 150
#define KH 4       // kernel//2
#define TC 4       // timesteps per k1 tile
#define TPB 3      // tiles per k1 block (plain rolled loop, no reg carrying)
#define TPG 5      // tp per fused-k2 block

#define ALD 72     // sA row stride in u16 (144 B, 16B-aligned; b128 reads 2-way free)
#define FLD 100    // sF row stride in f32

typedef __attribute__((ext_vector_type(4))) float f32x4;
typedef __attribute__((ext_vector_type(8))) short bf16x8;

static __device__ __forceinline__ unsigned short f2bf(float f) {
    unsigned u = __float_as_uint(f);
    unsigned r = (u + 0x7FFFu + ((u >> 16) & 1u)) >> 16;   // RNE
    return (unsigned short)r;
}
static __device__ __forceinline__ float bf2f(unsigned short h) {
    return __uint_as_float(((unsigned)h) << 16);
}
static __device__ __forceinline__ float bfLO(unsigned u) {
    return __uint_as_float(u << 16);
}
static __device__ __forceinline__ float bfHI(unsigned u) {
    return __uint_as_float(u & 0xffff0000u);
}

// ------- Kernel 0: Wext = [W | W@aT | W@pT] -> bf16 h/l, FRAGMENT-MAJOR -----
// 64 blocks: all blocks zero a slice of ssum; block 0 computes the Wext tables.
__global__ __launch_bounds__(256) void k0_prep(const float* __restrict__ W,
                                               const float* __restrict__ alpha,
                                               const float* __restrict__ phi,
                                               unsigned short* __restrict__ Wh,
                                               unsigned short* __restrict__ Wl,
                                               float* __restrict__ ssum) {
    const int tid = threadIdx.x;
    {
        int i = blockIdx.x * 256 + tid;
        if (i < 12800)
            reinterpret_cast<float4*>(ssum)[i] = (float4){0.f, 0.f, 0.f, 0.f};
    }
    if (blockIdx.x != 0) return;

    __shared__ float sW[64][64];
    __shared__ float sA[32][64];   // rows 0..15 alpha, 16..31 phi
    __shared__ float sWe[64][96];
    for (int i = tid; i < 1024; i += 256)
        reinterpret_cast<float4*>(&sW[0][0])[i] = reinterpret_cast<const float4*>(W)[i];
    for (int i = tid; i < 512; i += 256) {
        float4 v = (i < 256) ? reinterpret_cast<const float4*>(alpha)[i]
                             : reinterpret_cast<const float4*>(phi)[i - 256];
        reinterpret_cast<float4*>(&sA[0][0])[i] = v;
    }
    __syncthreads();
    for (int i = tid; i < 1024; i += 256) {           // copy W -> cols 0..63
        int ci = i >> 4, q = i & 15;
        *reinterpret_cast<float4*>(&sWe[ci][4 * q]) =
            reinterpret_cast<const float4*>(&sW[ci][0])[q];
    }
    for (int i = tid; i < 2048; i += 256) {           // dots -> cols 64..95
        int ci = i >> 5, j = i & 31;
        const float4* a = reinterpret_cast<const float4*>(&sW[ci][0]);
        const float4* b = reinterpret_cast<const float4*>(&sA[j][0]);
        float acc = 0.f;
#pragma unroll
        for (int q = 0; q < 16; ++q) {
            float4 u = a[q], w = b[q];
            acc += u.x * w.x + u.y * w.y + u.z * w.z + u.w * w.w;
        }
        sWe[ci][64 + j] = acc;
    }
    __syncthreads();
    for (int i = tid; i < 6144; i += 256) {
        int k = i / 96, c = i - 96 * k;
        float f = sWe[k][c];
        unsigned short h = f2bf(f);
        int off = (((k >> 3) * 96) + c) * 8 + (k & 7);
        Wh[off] = h;
        Wl[off] = f2bf(f - bf2f(h));
    }
}

// ------- Kernel 1: xwv(bf16)/xws1,xws2(bf16) via bf16 MFMA + fused colsum ---
// r27 proven rolled-loop structure (single dispatch wave). Score tables now
// stored bf16: upstream 3-pass h/l MFMA precision preserved; only the stored
// representation is quantized (delta-score ~0.015, softmax-safe).
__global__ __launch_bounds__(512) void k1_mfma(const float* __restrict__ x,
                                               const unsigned short* __restrict__ Bh,
                                               const unsigned short* __restrict__ Bl,
                                               unsigned short* __restrict__ xwv,
                                               unsigned short* __restrict__ xws1,
                                               unsigned short* __restrict__ xws2,
                                               float* __restrict__ ssum) {
    __shared__ __align__(16) char smem[40000];
    unsigned short (*sAh)[ALD] = reinterpret_cast<unsigned short(*)[ALD]>(smem);
    unsigned short (*sAl)[ALD] = reinterpret_cast<unsigned short(*)[ALD]>(smem + 18432);
    float (*sF)[FLD] = reinterpret_cast<float(*)[FLD]>(smem);   // barrier-separated reuse

    const int n  = blockIdx.y;
    const int tg = blockIdx.x;            // 0..24 -> tiles tg*3 .. tg*3+2
    const int tid = threadIdx.x;
    const int w    = tid >> 6;            // wave = M-tile 0..7
    const int lane = tid & 63;
    const int lm   = lane & 15;
    const int g    = lane >> 4;
    const int mc   = w * 16 + lm;
    const int cig  = tid & 15, tq = tid >> 4;

#pragma unroll 1
    for (int it = 0; it < TPB; ++it) {
        const int t0 = (tg * TPB + it) * TC;

        // ---- stage A: thread (tq, cig) loads 4 ci x 4 tv, packs, writes uint2 ----
        if (tid < 400) {
            const float* xp = x + (size_t)n * CC * TT * VV + (size_t)t0 * VV + 4 * tq;
            unsigned short mh[4][4], ml[4][4];
#pragma unroll
            for (int u = 0; u < 4; ++u) {
                const int ci = cig * 4 + u;
                float4 v = *reinterpret_cast<const float4*>(&xp[(size_t)ci * TT * VV]);
                unsigned short h0 = f2bf(v.x), h1 = f2bf(v.y), h2 = f2bf(v.z), h3 = f2bf(v.w);
                mh[0][u] = h0; mh[1][u] = h1; mh[2][u] = h2; mh[3][u] = h3;
                ml[0][u] = f2bf(v.x - bf2f(h0));
                ml[1][u] = f2bf(v.y - bf2f(h1));
                ml[2][u] = f2bf(v.z - bf2f(h2));
                ml[3][u] = f2bf(v.w - bf2f(h3));
            }
#pragma unroll
            for (int i = 0; i < 4; ++i) {
                *reinterpret_cast<uint2*>(&sAh[4 * tq + i][cig * 4]) =
                    *reinterpret_cast<const uint2*>(&mh[i][0]);
                *reinterpret_cast<uint2*>(&sAl[4 * tq + i][cig * 4]) =
                    *reinterpret_cast<const uint2*>(&ml[i][0]);
            }
        }
        __syncthreads();

        // ---- MFMA ----
        f32x4 acc[6];
#pragma unroll
        for (int b = 0; b < 6; ++b) acc[b] = (f32x4){0.f, 0.f, 0.f, 0.f};
#pragma unroll
        for (int kh = 0; kh < 2; ++kh) {
            const int kb = kh * 32 + g * 8;
            const int kc = kb >> 3;
            bf16x8 ah = *reinterpret_cast<const bf16x8*>(&sAh[mc][kb]);
            bf16x8 al = *reinterpret_cast<const bf16x8*>(&sAl[mc][kb]);
#pragma unroll
            for (int nt = 0; nt < 6; ++nt) {
                const int nc = nt * 16 + lm;
                bf16x8 bh = *reinterpret_cast<const bf16x8*>(&Bh[(size_t)(kc * 96 + nc) * 8]);
                acc[nt] = __builtin_amdgcn_mfma_f32_16x16x32_bf16(ah, bh, acc[nt], 0, 0, 0);
                if (nt >= 4) {   // score cols: h*l + l*h correction passes
                    bf16x8 bl = *reinterpret_cast<const bf16x8*>(&Bl[(size_t)(kc * 96 + nc) * 8]);
                    acc[nt] = __builtin_amdgcn_mfma_f32_16x16x32_bf16(ah, bl, acc[nt], 0, 0, 0);
                    acc[nt] = __builtin_amdgcn_mfma_f32_16x16x32_bf16(al, bh, acc[nt], 0, 0, 0);
                }
            }
        }
        __syncthreads();   // sA dead; reuse as sF

        // ---- stage accs to sF ----
#pragma unroll
        for (int j = 0; j < 4; ++j) {
            const int row = w * 16 + g * 4 + j;
            if (row < 100) {
#pragma unroll
                for (int nt = 0; nt < 6; ++nt)
                    sF[row][nt * 16 + lm] = acc[nt][j];
            }
        }
        __syncthreads();

        // ---- epilogue: colsum atomics + xwv/xws bf16 stores ----
        for (int i = tid; i < 1600; i += 512) {
            const int vv = i >> 6, c = i & 63;
            float s = sF[vv][c] + sF[vv + 25][c] + sF[vv + 50][c] + sF[vv + 75][c];
            atomicAdd(&ssum[((size_t)n * VV + vv) * CC + c], s);
        }
        for (int i = tid; i < 1600; i += 512) {
            const int row = i >> 4, q = i & 15;
            const int tloc = row / 25, vv = row - 25 * tloc;
            size_t dst = (((size_t)n * VV + vv) * TT + (t0 + tloc)) * CC + 4 * q;
            float4 v = *reinterpret_cast<const float4*>(&sF[row][4 * q]);
            ushort4 b = {f2bf(v.x), f2bf(v.y), f2bf(v.z), f2bf(v.w)};
            *reinterpret_cast<ushort4*>(&xwv[dst]) = b;
        }
        if (tid < 400) {   // xws2 (x2), bf16: all 100 rows, 4 u16 per thread
            const int row = tid >> 2, q = tid & 3;
            const int tloc = row / 25, vv = row - 25 * tloc;
            size_t dst = (((size_t)n * VV + vv) * TT + (t0 + tloc)) * 16 + 4 * q;
            float4 v = *reinterpret_cast<const float4*>(&sF[row][80 + 4 * q]);
            ushort4 b = {f2bf(v.x), f2bf(v.y), f2bf(v.z), f2bf(v.w)};
            *reinterpret_cast<ushort4*>(&xws2[dst]) = b;
        }
        if (tid < 200) {   // xws1 (x1), bf16: EVEN rows only
            const int re = tid >> 2, q = tid & 3;       // re 0..49
            const int te = re / 25, vv = re - 25 * te;  // te 0..1 -> tloc = 2*te
            const int tp = (t0 + 2 * te) >> 1;
            size_t dst = (((size_t)n * VV + vv) * TPOUT + tp) * 16 + 4 * q;
            float4 v = *reinterpret_cast<const float4*>(&sF[2 * te * 25 + vv][64 + 4 * q]);
            ushort4 b = {f2bf(v.x), f2bf(v.y), f2bf(v.z), f2bf(v.w)};
            *reinterpret_cast<ushort4*>(&xws1[dst]) = b;
        }
        __syncthreads();   // sF reads done -> sA writable next iteration
    }
}

// ------- Kernel 2 (fused attention + transpose): r24/r27 proven structure ---
// Score tables read as bf16 (2 uint4 loads per 16-vector + 1-op decodes).
__global__ __launch_bounds__(512) void k2_fused(const unsigned short* __restrict__ xwv,
                                                const unsigned short* __restrict__ xws1,
                                                const unsigned short* __restrict__ xws2,
                                                const float* __restrict__ ssum,
                                                float* __restrict__ out) {
    const int tpg = blockIdx.x;   // 0..29
    const int n   = blockIdx.y;   // 0..31
    const int tid = threadIdx.x;
    const int tp0 = tpg * TPG;

    __shared__ unsigned short sOut[TPG * VV][66];   // [tpl*25+v][c] bf16, pad 66
    __shared__ float sss[VV][CC];
    __shared__ float sscore[TPG][VV][9];
    __shared__ float scoef[TPG][VV][10];

    for (int i = tid; i < VV * CC; i += 512)
        (&sss[0][0])[i] = ssum[((size_t)n * VV) * CC + i];

    // ---- scores: x1 from xws1 (even-row table), x2 from xws2 (both bf16) ----
    for (int j = tid; j < TPG * VV * 9; j += 512) {
        const int tpl = j / (VV * 9);
        const int rem = j - tpl * (VV * 9);
        const int v = rem / 9, k = rem - 9 * v;
        const int t = 2 * (tp0 + tpl);
        const int s = t - KH + k;
        float sc = 0.f;
        if (s >= 0 && s < TT) {
            const size_t r = (size_t)n * VV + v;
            const uint4* p1 = reinterpret_cast<const uint4*>(&xws1[(r * TPOUT + tp0 + tpl) * 16]);
            const uint4* p2 = reinterpret_cast<const uint4*>(&xws2[(r * TT + s) * 16]);
#pragma unroll
            for (int h = 0; h < 2; ++h) {
                uint4 a = p1[h], b = p2[h];
                sc += bfLO(a.x) * bfLO(b.x) + bfHI(a.x) * bfHI(b.x);
                sc += bfLO(a.y) * bfLO(b.y) + bfHI(a.y) * bfHI(b.y);
                sc += bfLO(a.z) * bfLO(b.z) + bfHI(a.z) * bfHI(b.z);
                sc += bfLO(a.w) * bfLO(b.w) + bfHI(a.w) * bfHI(b.w);
            }
        }
        sscore[tpl][v][k] = sc;
    }
    __syncthreads();

    // ---- softmax coefficients: 125 (tpl, v) jobs ----
    for (int j = tid; j < TPG * VV; j += 512) {
        const int tpl = j / VV, v = j - tpl * VV;
        const int t = 2 * (tp0 + tpl);
        float m = 0.f;
        int nb = 0;
#pragma unroll
        for (int k = 0; k < 9; ++k) {
            int s = t - KH + k;
            if (s >= 0 && s < TT) { nb++; m = fmaxf(m, sscore[tpl][v][k]); }
        }
        float wbg = __expf(-m);
        float Z = (float)(TT - nb) * wbg;
        float e[9];
#pragma unroll
        for (int k = 0; k < 9; ++k) {
            int s = t - KH + k;
            float ek = (s >= 0 && s < TT) ? __expf(sscore[tpl][v][k] - m) : 0.f;
            e[k] = ek;
            Z += ek;
        }
        float inv = 1.f / Z;
#pragma unroll
        for (int k = 0; k < 9; ++k) {
            int s = t - KH + k;
            scoef[tpl][v][k] = (s >= 0 && s < TT) ? (e[k] - wbg) * inv : 0.f;
        }
        scoef[tpl][v][9] = wbg * inv;
    }
    __syncthreads();

    // ---- 9-tap accumulation: thread = (w, 8-c group); uint4 tap loads ----
    for (int j = tid; j < TPG * VV * 8; j += 512) {
        const int w  = j >> 3;              // tpl*25 + v
        const int cg = j & 7;               // c = cg*8 .. cg*8+7
        const int tpl = w / VV, v = w - tpl * VV;
        const int t = 2 * (tp0 + tpl);
        const size_t rbase = ((size_t)n * VV + v) * TT;
        const int c0 = cg * 8;

        float val[8];
        {
            const float cbg = scoef[tpl][v][9];
#pragma unroll
            for (int i = 0; i < 8; ++i) val[i] = cbg * sss[v][c0 + i];
        }
#pragma unroll
        for (int k = 0; k < 9; ++k) {
            int s = t - KH + k;
            s = min(max(s, 0), TT - 1);     // coef is 0 for invalid slots
            const float cf = scoef[tpl][v][k];
            uint4 u = *reinterpret_cast<const uint4*>(&xwv[(rbase + s) * CC + c0]);
            val[0] = fmaf(cf, bfLO(u.x), val[0]);
            val[1] = fmaf(cf, bfHI(u.x), val[1]);
            val[2] = fmaf(cf, bfLO(u.y), val[2]);
            val[3] = fmaf(cf, bfHI(u.y), val[3]);
            val[4] = fmaf(cf, bfLO(u.z), val[4]);
            val[5] = fmaf(cf, bfHI(u.z), val[5]);
            val[6] = fmaf(cf, bfLO(u.w), val[6]);
            val[7] = fmaf(cf, bfHI(u.w), val[7]);
        }
#pragma unroll
        for (int i = 0; i < 8; ++i) sOut[w][c0 + i] = f2bf(val[i]);
    }
    __syncthreads();

    // ---- store: v-major, 125 contiguous floats (500 B) per c ----
    float* dst = out + ((size_t)n * CC * TPOUT * VV + (size_t)tp0 * VV);
    for (int j = tid; j < CC * TPG * VV; j += 512) {
        const int c = j / (TPG * VV);
        const int w = j - c * (TPG * VV);   // tpl*25 + v
        dst[(size_t)c * (TPOUT * VV) + w] = bf2f(sOut[w][c]);
    }
}

extern "C" void kernel_launch(void* const* d_in, const int* in_sizes, int n_in,
                              void* d_out, int out_size, void* d_ws, size_t ws_size,
                              hipStream_t stream) {
    const float* x     = (const float*)d_in[0];
    const float* W     = (const float*)d_in[1];
    const float* alpha = (const float*)d_in[2];
    const float* phi   = (const float*)d_in[3];
    float* out = (float*)d_out;

    float* ssum = (float*)d_ws;                                        // 800*64 f32
    unsigned short* xws2 = (unsigned short*)(ssum + (size_t)800 * 64); // 800*300*16 u16
    unsigned short* xws1 = xws2 + (size_t)800 * 300 * 16;              // 800*150*16 u16
    unsigned short* xwv  = xws1 + (size_t)800 * 150 * 16;              // 800*300*64 u16
    unsigned short* Wh   = xwv + (size_t)800 * 300 * CC;               // 6144 u16
    unsigned short* Wl   = Wh + 6144;                                  // (~42.5 MB total)

    k0_prep<<<64, 256, 0, stream>>>(W, alpha, phi, Wh, Wl, ssum);
    dim3 g1(TT / (TC * TPB), NB);                         // 25 x 32 = 800 blocks
    k1_mfma<<<g1, 512, 0, stream>>>(x, Wh, Wl, xwv, xws1, xws2, ssum);
    dim3 g2(TPOUT / TPG, NB);
    k2_fused<<<g2, 512, 0, stream>>>(xwv, xws1, xws2, ssum, out);
}